// Round 3
// baseline (1474.030 us; speedup 1.0000x reference)
//
#include <hip/hip_runtime.h>
#include <hip/hip_bf16.h>

#define B_   4
#define LD_  1024
#define LE_  1024
#define D_   256
#define H_   8
#define DK_  32
#define DFF_ 1024
#define NL_  6
#define NTOK (B_ * LD_)   // 4096 decoder tokens; encoder also 4*1024 = 4096
#define M1E  1048576      // NTOK * D_ elements

typedef __hip_bfloat16 bf16;
typedef __bf16 bf16_t;
typedef bf16_t bf16x8 __attribute__((ext_vector_type(8)));
typedef bf16_t bf16x4 __attribute__((ext_vector_type(4)));
typedef float  f32x4  __attribute__((ext_vector_type(4)));

__device__ __forceinline__ float bits2f(unsigned short u) {
    union { unsigned int i; float f; } w; w.i = ((unsigned int)u) << 16; return w.f;
}
// dtype-flexible scalar load from tensor base + element index
__device__ __forceinline__ float ldx(const void* p, size_t i, int f32) {
    if (f32) return ((const float*)p)[i];
    return bits2f(((const unsigned short*)p)[i]);
}

// ---------------------------------------------------------------------------
// Detect input dtype (bf16 vs fp32). flag: 1=fp32, 0=bf16.
__global__ __launch_bounds__(256) void detect_kernel(
    const void* __restrict__ enc, int* __restrict__ flag)
{
    __shared__ int bad;
    if (threadIdx.x == 0) bad = 0;
    __syncthreads();
    const unsigned short* u = (const unsigned short*)enc;
    int b = 0;
    for (int i = threadIdx.x; i < 4096; i += 256) {
        unsigned short e = (u[i] >> 7) & 0xFF;
        if (e >= 142) b = 1;
    }
    if (b) atomicOr(&bad, 1);
    __syncthreads();
    if (threadIdx.x == 0) *flag = bad;
}

// ---------------------------------------------------------------------------
__global__ __launch_bounds__(256) void embed_kernel(
    const void* __restrict__ dec, const void* __restrict__ Wt,
    const void* __restrict__ bt, float* __restrict__ x, const int* __restrict__ flag)
{
    int f32 = *flag;
    int i = blockIdx.x * 256 + threadIdx.x;     // over NTOK * D_
    int d = i & (D_ - 1);
    int t = i >> 8;
    float a0 = ldx(dec, t * 3 + 0, f32);
    float a1 = ldx(dec, t * 3 + 1, f32);
    float a2 = ldx(dec, t * 3 + 2, f32);
    x[i] = ldx(bt, d, f32) + a0 * ldx(Wt, 0 * D_ + d, f32)
         + a1 * ldx(Wt, 1 * D_ + d, f32) + a2 * ldx(Wt, 2 * D_ + d, f32);
}

__global__ __launch_bounds__(256) void conv_kernel(
    const void* __restrict__ in, float* __restrict__ out, const int* __restrict__ flag)
{
    int f32 = *flag;
    int i = blockIdx.x * 256 + threadIdx.x;
    out[i] = ldx(in, i, f32);
}

// build PE table [1024][256] once
__global__ __launch_bounds__(256) void pe_build_kernel(float* __restrict__ pe)
{
    int i = blockIdx.x * 256 + threadIdx.x;     // over LD_*D_ = 262144
    int d = i & (D_ - 1);
    int pos = i >> 8;
    int j = d & 127;
    float inv = powf(10000.0f, -2.0f * (float)j / (float)D_);
    float s = (float)pos * inv;
    pe[i] = (d < 128) ? sinf(s) : cosf(s);
}

__global__ __launch_bounds__(256) void add_pe_kernel(
    float* __restrict__ x, const float* __restrict__ pe)
{
    int i = blockIdx.x * 256 + threadIdx.x;
    x[i] += pe[i & (LD_ * D_ - 1)];
}

// ---------------------------------------------------------------------------
// MFMA GEMM: C = A @ W + bias (optional relu). A fp32 [M,K]; W,bias dtype per
// flag; wOff/bOff = element offsets of the layer slice. z-batched over up to 3
// independent (A,W,bias,C) tuples.
//
// mode 0: C fp32 [M][N] (+optional relu)
// mode 1: attention-prep epilogue (N==256):
//   z==0: Q -> (q+b)*scale split to hi/lo bf16: C[idx], C[M1E+idx]
//   z==1: K -> split hi/lo bf16 likewise
//   z==2: V -> bf16, TRANSPOSED: C[(size_t)n * 4096 + m]  (Vt layout [256][4096])
// Splits are bit-identical to the former in-fattn conversion -> numerics equal.
__global__ __launch_bounds__(256) void gemm3_kernel(
    const float* __restrict__ A0, const float* __restrict__ A1, const float* __restrict__ A2,
    const void* __restrict__ W0, const void* __restrict__ W1, const void* __restrict__ W2,
    const void* __restrict__ bias0, const void* __restrict__ bias1, const void* __restrict__ bias2,
    float* __restrict__ C0, float* __restrict__ C1, float* __restrict__ C2,
    size_t wOff, size_t bOff,
    int M, int N, int K, int relu, int mode, const int* __restrict__ flag)
{
    const int f32 = *flag;
    const int z = blockIdx.z;
    const float* A = (z == 0) ? A0 : (z == 1) ? A1 : A2;
    const void*  W = (z == 0) ? W0 : (z == 1) ? W1 : W2;
    const void*  bias = (z == 0) ? bias0 : (z == 1) ? bias1 : bias2;
    float* C = (z == 0) ? C0 : (z == 1) ? C1 : C2;

    __shared__ __align__(16) bf16_t Ahi[32][40];
    __shared__ __align__(16) bf16_t Alo[32][40];
    __shared__ __align__(16) bf16_t Whi[64][40];
    __shared__ __align__(16) bf16_t Wlo[64][40];

    const int tid = threadIdx.x;
    const int m0 = blockIdx.y * 32, n0 = blockIdx.x * 64;
    const int w = tid >> 6, l = tid & 63, l15 = l & 15, lg = l >> 4;
    const int wr = w >> 1, wc = w & 1;

    // A staging: thread -> (row 0..31, 4-float group)
    const int ar = tid >> 3, ac = (tid & 7) * 4;
    // W staging: thread -> (col n 0..63, k-block 0..3); swizzled block index
    const int wn = tid & 63, wkg = tid >> 6;
    const int wkb = 8 * (wkg ^ ((wn >> 3) & 3));

    // fragment read indices (hoisted)
    const int fa = 16 * wr + l15;
    const int c0 = 32 * wc + l15, c1 = c0 + 16;
    const int kb0 = 8 * (lg ^ ((c0 >> 3) & 3));
    const int kb1 = 8 * (lg ^ ((c1 >> 3) & 3));

    f32x4 acc0 = {0.f, 0.f, 0.f, 0.f};
    f32x4 acc1 = {0.f, 0.f, 0.f, 0.f};

    // prefetch K-step 0
    float4 av = *(const float4*)&A[(size_t)(m0 + ar) * K + ac];
    float wf[8];
#pragma unroll
    for (int j = 0; j < 8; ++j)
        wf[j] = ldx(W, wOff + (size_t)(8 * wkg + j) * N + n0 + wn, f32);

    for (int k0 = 0; k0 < K; k0 += 32) {
        __syncthreads();
        {   // convert staged regs -> hi/lo LDS
            float af[4] = {av.x, av.y, av.z, av.w};
            bf16x4 h4, l4;
#pragma unroll
            for (int j = 0; j < 4; ++j) {
                bf16_t hv = (bf16_t)af[j];
                h4[j] = hv;
                l4[j] = (bf16_t)(af[j] - (float)hv);
            }
            *(bf16x4*)&Ahi[ar][ac] = h4;
            *(bf16x4*)&Alo[ar][ac] = l4;
            bf16x8 h8, l8;
#pragma unroll
            for (int j = 0; j < 8; ++j) {
                bf16_t hv = (bf16_t)wf[j];
                h8[j] = hv;
                l8[j] = (bf16_t)(wf[j] - (float)hv);
            }
            *(bf16x8*)&Whi[wn][wkb] = h8;
            *(bf16x8*)&Wlo[wn][wkb] = l8;
        }
        __syncthreads();

        // prefetch next K-step while MFMAs run
        if (k0 + 32 < K) {
            av = *(const float4*)&A[(size_t)(m0 + ar) * K + k0 + 32 + ac];
#pragma unroll
            for (int j = 0; j < 8; ++j)
                wf[j] = ldx(W, wOff + (size_t)(k0 + 32 + 8 * wkg + j) * N + n0 + wn, f32);
        }

        bf16x8 ah = *(const bf16x8*)&Ahi[fa][8 * lg];
        bf16x8 al = *(const bf16x8*)&Alo[fa][8 * lg];
        bf16x8 bh0 = *(const bf16x8*)&Whi[c0][kb0];
        bf16x8 bl0 = *(const bf16x8*)&Wlo[c0][kb0];
        bf16x8 bh1 = *(const bf16x8*)&Whi[c1][kb1];
        bf16x8 bl1 = *(const bf16x8*)&Wlo[c1][kb1];
        acc0 = __builtin_amdgcn_mfma_f32_16x16x32_bf16(ah, bh0, acc0, 0, 0, 0);
        acc0 = __builtin_amdgcn_mfma_f32_16x16x32_bf16(al, bh0, acc0, 0, 0, 0);
        acc0 = __builtin_amdgcn_mfma_f32_16x16x32_bf16(ah, bl0, acc0, 0, 0, 0);
        acc1 = __builtin_amdgcn_mfma_f32_16x16x32_bf16(ah, bh1, acc1, 0, 0, 0);
        acc1 = __builtin_amdgcn_mfma_f32_16x16x32_bf16(al, bh1, acc1, 0, 0, 0);
        acc1 = __builtin_amdgcn_mfma_f32_16x16x32_bf16(ah, bl1, acc1, 0, 0, 0);
    }

    // epilogue: C/D layout col=l15, row=4*lg+r
    const int cm = m0 + 16 * wr + 4 * lg;
    const int cn = n0 + 32 * wc + l15;
    const float b0v = ldx(bias, bOff + cn, f32);
    const float b1v = ldx(bias, bOff + cn + 16, f32);
    if (mode == 0) {
#pragma unroll
        for (int r = 0; r < 4; ++r) {
            float v0 = acc0[r] + b0v;
            float v1 = acc1[r] + b1v;
            if (relu) { v0 = fmaxf(v0, 0.f); v1 = fmaxf(v1, 0.f); }
            C[(size_t)(cm + r) * N + cn]      = v0;
            C[(size_t)(cm + r) * N + cn + 16] = v1;
        }
    } else {
        bf16_t* Cb = (bf16_t*)C;
        const float qs = (z == 0) ? 0.17677669529663687f : 1.0f;   // 1/sqrt(32)
#pragma unroll
        for (int r = 0; r < 4; ++r) {
            float v0 = (acc0[r] + b0v) * qs;
            float v1 = (acc1[r] + b1v) * qs;
            if (z < 2) {
                size_t i0 = (size_t)(cm + r) * 256 + cn;
                bf16_t h0 = (bf16_t)v0;
                Cb[i0]       = h0;
                Cb[M1E + i0] = (bf16_t)(v0 - (float)h0);
                bf16_t h1 = (bf16_t)v1;
                Cb[i0 + 16]       = h1;
                Cb[M1E + i0 + 16] = (bf16_t)(v1 - (float)h1);
            } else {
                Cb[(size_t)cn * 4096 + (cm + r)]        = (bf16_t)v0;
                Cb[(size_t)(cn + 16) * 4096 + (cm + r)] = (bf16_t)v1;
            }
        }
    }
}

// ---------------------------------------------------------------------------
// Barrier-free MFMA flash attention. grid (LD/64, H, B), 256 thr = 4 waves;
// wave w owns q rows qt*64 + w*16 .. +15, fully independent (no __syncthreads).
// Operands are pre-split bf16 (Qb/Kb: hi at [i], lo at [M1E+i]; Vt [256][4096]
// transposed) so all fragments are direct 16B global loads; per-(b,h) tile
// working set ~12KB -> L1/L2-resident. Only LDS: wave-private P transpose.
__global__ __launch_bounds__(256) void fattn2_kernel(
    const bf16_t* __restrict__ Qb, const bf16_t* __restrict__ Kb,
    const bf16_t* __restrict__ Vt, float* __restrict__ O,
    const int* __restrict__ mask, int causal)
{
    __shared__ __align__(16) bf16_t Ps[4][16][72];

    const int tid = threadIdx.x;
    const int qt = blockIdx.x, h = blockIdx.y, b = blockIdx.z;
    const int w = tid >> 6, l = tid & 63, l15 = l & 15, lg = l >> 4;

    // Q fragment (scale pre-folded by gemm3 mode-1)
    const size_t qoff = ((size_t)(b * LD_ + qt * 64 + w * 16 + l15)) * D_ + h * DK_ + 8 * lg;
    const bf16x8 qh = *(const bf16x8*)(Qb + qoff);
    const bf16x8 ql = *(const bf16x8*)(Qb + M1E + qoff);

    float mrow[4], lsum[4];
#pragma unroll
    for (int r = 0; r < 4; ++r) { mrow[r] = -3.0e38f; lsum[r] = 0.0f; }
    f32x4 o0 = {0.f, 0.f, 0.f, 0.f};   // dv 0..15,  rows 4*lg+r
    f32x4 o1 = {0.f, 0.f, 0.f, 0.f};   // dv 16..31

    const int nkt = causal ? (qt + 1) : (LE_ / 64);

    for (int kt = 0; kt < nkt; ++kt) {
        // ---- all loads issued up front (no barriers -> free scheduling) ----
        const size_t kbase = ((size_t)(b * LE_ + kt * 64)) * D_ + h * DK_ + 8 * lg;
        bf16x8 kh[4], kl[4];
#pragma unroll
        for (int nt = 0; nt < 4; ++nt) {
            size_t off = kbase + (size_t)(nt * 16 + l15) * D_;
            kh[nt] = *(const bf16x8*)(Kb + off);
            kl[nt] = *(const bf16x8*)(Kb + M1E + off);
        }
        const bf16_t* vrow0 = Vt + (size_t)(h * DK_ + l15) * 4096 + b * 1024 + kt * 64;
        const bf16_t* vrow1 = vrow0 + (size_t)16 * 4096;
        bf16x8 vb00 = *(const bf16x8*)(vrow0 + 8 * lg);
        bf16x8 vb10 = *(const bf16x8*)(vrow0 + 32 + 8 * lg);
        bf16x8 vb01 = *(const bf16x8*)(vrow1 + 8 * lg);
        bf16x8 vb11 = *(const bf16x8*)(vrow1 + 32 + 8 * lg);
        int msk[4];
#pragma unroll
        for (int nt = 0; nt < 4; ++nt)
            msk[nt] = mask[b * 1024 + kt * 64 + nt * 16 + l15];

        // ---- S = Q·K^T (split bf16: qh*kh + qh*kl + ql*kh) ----
        f32x4 s[4];
#pragma unroll
        for (int nt = 0; nt < 4; ++nt) {
            f32x4 acc = {0.f, 0.f, 0.f, 0.f};
            acc = __builtin_amdgcn_mfma_f32_16x16x32_bf16(qh, kh[nt], acc, 0, 0, 0);
            acc = __builtin_amdgcn_mfma_f32_16x16x32_bf16(qh, kl[nt], acc, 0, 0, 0);
            acc = __builtin_amdgcn_mfma_f32_16x16x32_bf16(ql, kh[nt], acc, 0, 0, 0);
            s[nt] = acc;
        }

        // ---- mask + online softmax (rows 4*lg+r) ----
        const int row0 = qt * 64 + w * 16 + 4 * lg;
        float pm[4] = {-3.0e38f, -3.0e38f, -3.0e38f, -3.0e38f};
#pragma unroll
        for (int nt = 0; nt < 4; ++nt) {
            int col = kt * 64 + nt * 16 + l15;
#pragma unroll
            for (int r = 0; r < 4; ++r) {
                bool dead = (msk[nt] != 0) || (causal && col > row0 + r);
                float v = dead ? -1e30f : s[nt][r];
                s[nt][r] = v;
                pm[r] = fmaxf(pm[r], v);
            }
        }
#pragma unroll
        for (int r = 0; r < 4; ++r) {
            pm[r] = fmaxf(pm[r], __shfl_xor(pm[r], 1));
            pm[r] = fmaxf(pm[r], __shfl_xor(pm[r], 2));
            pm[r] = fmaxf(pm[r], __shfl_xor(pm[r], 4));
            pm[r] = fmaxf(pm[r], __shfl_xor(pm[r], 8));
        }
        float alpha[4], psum[4];
#pragma unroll
        for (int r = 0; r < 4; ++r) {
            float mnew = fmaxf(mrow[r], pm[r]);
            alpha[r] = __expf(mrow[r] - mnew);
            mrow[r] = mnew;
            psum[r] = 0.0f;
        }
#pragma unroll
        for (int nt = 0; nt < 4; ++nt) {
#pragma unroll
            for (int r = 0; r < 4; ++r) {
                float p = __expf(s[nt][r] - mrow[r]);
                Ps[w][4 * lg + r][nt * 16 + l15] = (bf16_t)p;
                psum[r] += p;
            }
        }
#pragma unroll
        for (int r = 0; r < 4; ++r) {
            psum[r] += __shfl_xor(psum[r], 1);
            psum[r] += __shfl_xor(psum[r], 2);
            psum[r] += __shfl_xor(psum[r], 4);
            psum[r] += __shfl_xor(psum[r], 8);
            lsum[r] = lsum[r] * alpha[r] + psum[r];
            o0[r] *= alpha[r];
            o1[r] *= alpha[r];
        }

        // ---- O += P·V (P transposed via wave-private LDS; same-wave ds
        //      ordering handled by lgkmcnt, no barrier) ----
        {
            bf16x8 pa0 = *(const bf16x8*)&Ps[w][l15][8 * lg];
            o0 = __builtin_amdgcn_mfma_f32_16x16x32_bf16(pa0, vb00, o0, 0, 0, 0);
            o1 = __builtin_amdgcn_mfma_f32_16x16x32_bf16(pa0, vb01, o1, 0, 0, 0);
            bf16x8 pa1 = *(const bf16x8*)&Ps[w][l15][32 + 8 * lg];
            o0 = __builtin_amdgcn_mfma_f32_16x16x32_bf16(pa1, vb10, o0, 0, 0, 0);
            o1 = __builtin_amdgcn_mfma_f32_16x16x32_bf16(pa1, vb11, o1, 0, 0, 0);
        }
    }

    // ---- epilogue ----
    float inv[4];
#pragma unroll
    for (int r = 0; r < 4; ++r) inv[r] = 1.0f / lsum[r];
    float* op = O + ((size_t)(b * LD_ + qt * 64 + w * 16 + 4 * lg)) * D_ + h * DK_ + l15;
#pragma unroll
    for (int r = 0; r < 4; ++r) {
        op[(size_t)r * D_ + 0]  = o0[r] * inv[r];
        op[(size_t)r * D_ + 16] = o1[r] * inv[r];
    }
}

// ---------------------------------------------------------------------------
// x = LayerNorm(t + x) * g + b ; one wave per token, shfl reduce, no barriers.
__global__ __launch_bounds__(256) void ln_res_kernel(
    const float* __restrict__ t, float* __restrict__ x,
    const void* __restrict__ g, const void* __restrict__ bt,
    size_t gbOff, const int* __restrict__ flag)
{
    int f32 = *flag;
    int tok = blockIdx.x * 4 + (threadIdx.x >> 6);
    int l = threadIdx.x & 63;
    size_t base = (size_t)tok * D_ + 4 * l;
    f32x4 tv = *(const f32x4*)(t + base);
    f32x4 xv = *(const f32x4*)(x + base);
    f32x4 v;
    float s1 = 0.f, s2 = 0.f;
#pragma unroll
    for (int j = 0; j < 4; ++j) {
        v[j] = tv[j] + xv[j];
        s1 += v[j];
        s2 += v[j] * v[j];
    }
#pragma unroll
    for (int off = 1; off < 64; off <<= 1) {
        s1 += __shfl_xor(s1, off);
        s2 += __shfl_xor(s2, off);
    }
    float mean = s1 * (1.0f / 256.0f);
    float var  = s2 * (1.0f / 256.0f) - mean * mean;
    float inv  = 1.0f / sqrtf(var + 1e-5f);
    f32x4 out;
#pragma unroll
    for (int j = 0; j < 4; ++j)
        out[j] = (v[j] - mean) * inv * ldx(g, gbOff + 4 * l + j, f32)
               + ldx(bt, gbOff + 4 * l + j, f32);
    *(f32x4*)(x + base) = out;
}

__global__ __launch_bounds__(256) void cast_kernel(
    const float* __restrict__ x, void* __restrict__ out, const int* __restrict__ flag)
{
    int f32 = *flag;
    int i = blockIdx.x * 256 + threadIdx.x;
    if (f32) ((float*)out)[i] = x[i];
    else ((bf16*)out)[i] = __float2bfloat16(x[i]);
}

// ---------------------------------------------------------------------------
extern "C" void kernel_launch(void* const* d_in, const int* in_sizes, int n_in,
                              void* d_out, int out_size, void* d_ws, size_t ws_size,
                              hipStream_t stream)
{
    const void* enc       = d_in[0];
    const void* dec       = d_in[1];
    const int*  enc_masks = (const int*)d_in[2];
    const int*  dec_masks = (const int*)d_in[3];
    const void* W_tgt = d_in[4];
    const void* b_tgt = d_in[5];
    const void* sa_Wq = d_in[6];
    const void* sa_bq = d_in[7];
    const void* sa_Wk = d_in[8];
    const void* sa_bk = d_in[9];
    const void* sa_Wv = d_in[10];
    const void* sa_bv = d_in[11];
    const void* sa_Wo = d_in[12];
    const void* sa_bo = d_in[13];
    const void* sa_ln_g = d_in[14];
    const void* sa_ln_b = d_in[15];
    const void* ca_Wq = d_in[16];
    const void* ca_bq = d_in[17];
    const void* ca_Wk = d_in[18];
    const void* ca_bk = d_in[19];
    const void* ca_Wv = d_in[20];
    const void* ca_bv = d_in[21];
    const void* ca_Wo = d_in[22];
    const void* ca_bo = d_in[23];
    const void* ca_ln_g = d_in[24];
    const void* ca_ln_b = d_in[25];
    const void* ff_W1 = d_in[26];
    const void* ff_b1 = d_in[27];
    const void* ff_W2 = d_in[28];
    const void* ff_b2 = d_in[29];
    const void* ff_ln_g = d_in[30];
    const void* ff_ln_b = d_in[31];

    const size_t M1 = (size_t)NTOK * D_;        // 1M floats
    float* ws = (float*)d_ws;
    float* x     = ws;                          // [0,1) M1
    float* t     = ws + 1 * M1;                 // [1,2)
    float* ctx   = ws + 2 * M1;                 // [2,3)
    float* enc_f = ws + 3 * M1;                 // [3,4)
    float* h     = ws + 4 * M1;                 // [4,8): NTOK x DFF fp32
    // attention operand buffers alias h (attn phase and FFN phase are disjoint)
    bf16_t* qbuf = (bf16_t*)(ws + 4 * M1);      // hi[M1E] + lo[M1E] = 1 M1 floats
    bf16_t* kbuf = (bf16_t*)(ws + 5 * M1);      // hi[M1E] + lo[M1E]
    bf16_t* vtbuf= (bf16_t*)(ws + 6 * M1);      // [256][4096] bf16 = 0.5 M1
    float* pe    = ws + 8 * M1;                 // [8, 8.25): LD_*D_ floats
    int*   flag  = (int*)(ws + 9 * M1);

    const int nElem = NTOK * D_;                // 1,048,576

    detect_kernel<<<1, 256, 0, stream>>>(enc, flag);
    embed_kernel<<<nElem / 256, 256, 0, stream>>>(dec, W_tgt, b_tgt, x, flag);
    conv_kernel<<<nElem / 256, 256, 0, stream>>>(enc, enc_f, flag);
    pe_build_kernel<<<(LD_ * D_) / 256, 256, 0, stream>>>(pe);

    dim3 gProj(D_ / 64, NTOK / 32, 3);          // (4,128,3)
    dim3 gOne(D_ / 64, NTOK / 32, 1);           // (4,128,1)
    dim3 gFF1(DFF_ / 64, NTOK / 32, 1);         // (16,128,1)
    dim3 gAttn(LD_ / 64, H_, B_);               // (16,8,4)

    for (int i = 0; i < NL_; ++i) {
        const size_t wOff  = (size_t)i * D_ * D_;      // element offsets
        const size_t bOff  = (size_t)i * D_;
        const size_t f1Off = (size_t)i * D_ * DFF_;
        const size_t f1bOff= (size_t)i * DFF_;

        add_pe_kernel<<<nElem / 256, 256, 0, stream>>>(x, pe);

        // --- self attention ---
        gemm3_kernel<<<gProj, 256, 0, stream>>>(
            x, x, x, sa_Wq, sa_Wk, sa_Wv, sa_bq, sa_bk, sa_bv,
            (float*)qbuf, (float*)kbuf, (float*)vtbuf,
            wOff, bOff, NTOK, D_, D_, 0, 1, flag);
        fattn2_kernel<<<gAttn, 256, 0, stream>>>(qbuf, kbuf, vtbuf, ctx, dec_masks, 1);
        gemm3_kernel<<<gOne, 256, 0, stream>>>(
            ctx, ctx, ctx, sa_Wo, sa_Wo, sa_Wo, sa_bo, sa_bo, sa_bo,
            t, t, t, wOff, bOff, NTOK, D_, D_, 0, 0, flag);
        ln_res_kernel<<<NTOK / 4, 256, 0, stream>>>(t, x, sa_ln_g, sa_ln_b, bOff, flag);

        // --- cross attention ---
        gemm3_kernel<<<gProj, 256, 0, stream>>>(
            x, enc_f, enc_f, ca_Wq, ca_Wk, ca_Wv, ca_bq, ca_bk, ca_bv,
            (float*)qbuf, (float*)kbuf, (float*)vtbuf,
            wOff, bOff, NTOK, D_, D_, 0, 1, flag);
        fattn2_kernel<<<gAttn, 256, 0, stream>>>(qbuf, kbuf, vtbuf, ctx, enc_masks, 0);
        gemm3_kernel<<<gOne, 256, 0, stream>>>(
            ctx, ctx, ctx, ca_Wo, ca_Wo, ca_Wo, ca_bo, ca_bo, ca_bo,
            t, t, t, wOff, bOff, NTOK, D_, D_, 0, 0, flag);
        ln_res_kernel<<<NTOK / 4, 256, 0, stream>>>(t, x, ca_ln_g, ca_ln_b, bOff, flag);

        // --- FFN ---
        gemm3_kernel<<<gFF1, 256, 0, stream>>>(
            x, x, x, ff_W1, ff_W1, ff_W1, ff_b1, ff_b1, ff_b1,
            h, h, h, f1Off, f1bOff, NTOK, DFF_, D_, 1, 0, flag);
        gemm3_kernel<<<gOne, 256, 0, stream>>>(
            h, h, h, ff_W2, ff_W2, ff_W2, ff_b2, ff_b2, ff_b2,
            t, t, t, f1Off, bOff, NTOK, D_, DFF_, 0, 0, flag);
        ln_res_kernel<<<NTOK / 4, 256, 0, stream>>>(t, x, ff_ln_g, ff_ln_b, bOff, flag);
    }

    cast_kernel<<<nElem / 256, 256, 0, stream>>>(x, d_out, flag);
}